// Round 1
// baseline (662.393 us; speedup 1.0000x reference)
//
#include <hip/hip_runtime.h>

typedef float floatx4 __attribute__((ext_vector_type(4)));
typedef short short8 __attribute__((ext_vector_type(8)));
typedef unsigned short ushort_t;

#define AS1 __attribute__((address_space(1)))
#define AS3 __attribute__((address_space(3)))

__device__ __forceinline__ void gload_lds16(const ushort_t* g, ushort_t* l) {
    __builtin_amdgcn_global_load_lds((const AS1 unsigned int*)g, (AS3 unsigned int*)l, 16, 0, 0);
}

__device__ __forceinline__ ushort_t f2bf(float f) {
    union { float f; unsigned u; } v; v.f = f;
    unsigned r = v.u + 0x7FFFu + ((v.u >> 16) & 1u);
    return (ushort_t)(r >> 16);
}

#define KDIM 512
#define LOG2E 1.44269504f

// ws element offsets (bf16 elems). attb reuses xb's region (xb dead after GEMM1).
// q/k/v are (B,T,512) row-major bf16.
#define XB_OFF   0ull
#define ATT_OFF  0ull
#define WQKV_OFF 33554432ull
#define WOUT_OFF 34340864ull
#define QB_OFF   34603008ull
#define KB_OFF   68157440ull
#define VB_OFF   101711872ull

// ---------------- convert fp32 -> bf16 (x, Wqkv, Wout concatenated) ----------------
__global__ __launch_bounds__(256) void convert_k(
    const float* __restrict__ x, const float* __restrict__ wqkv,
    const float* __restrict__ wout, ushort_t* __restrict__ dst)
{
    size_t i = (size_t)blockIdx.x * 256 + threadIdx.x;
    size_t e = i * 4;
    const float* s; size_t o;
    if (e < 33554432ull)      { s = x;    o = e; }
    else if (e < 34340864ull) { s = wqkv; o = e - 33554432ull; }
    else                      { s = wout; o = e - 34340864ull; }
    float4 v = *(const float4*)(s + o);
    ushort4 r;
    r.x = f2bf(v.x); r.y = f2bf(v.y); r.z = f2bf(v.z); r.w = f2bf(v.w);
    *(ushort4*)(dst + e) = r;
}

// ---------------- GEMM C = A(MxK) * B(NxK)^T, bf16 MFMA ----------------
// 256x256 tile, 512 threads (8 waves, 2x4), BK=32, 4-deep LDS ring buffer,
// counted vmcnt (never 0 in main loop), raw s_barrier, setprio around MFMA.
// Per phase: stage K-tile t+3 (4x global_load_lds16) | ds_read 12 frags of tile t
//            | 32 MFMA | vmcnt(8) | s_barrier.
// Ring-of-4 race safety: tile t+3 overwrites buf[(t+3)&3] == buf[(t-1)&3], whose
// reads (tile t-1) finished (lgkmcnt0 before that phase's barrier) before this
// phase's stage issues.

// stage one K-tile (256 rows x 32 cols) of A and B into ring slot
__device__ __forceinline__ void stage_tile(const ushort_t* __restrict__ Ag,
    const ushort_t* __restrict__ Bg, ushort_t* As, ushort_t* Bs,
    const int k0, const int tid)
{
#pragma unroll
    for (int rnd = 0; rnd < 2; rnd++) {
        const int e = rnd * 512 + tid;          // 8-elem chunk id, [0,1024)
        const int row = e >> 2, c8 = (e & 3) << 3;
        gload_lds16(Ag + (size_t)row * KDIM + k0 + c8, As + e * 8);  // LDS dest: base + lane*16B (wave-uniform rule OK)
        gload_lds16(Bg + (size_t)row * KDIM + k0 + c8, Bs + e * 8);
    }
}

// 12 ds_read_b128 + 32 MFMA for one K-tile.
// [256][32] rows are 64B => frag reads hit 8 lanes per 4-bank slot: conflict-free.
__device__ __forceinline__ void compute_tile(const ushort_t* Ab, const ushort_t* Bb,
    floatx4 (&acc)[8][4], const int wm, const int wn, const int l16, const int quad)
{
    short8 af[8], bfr[4];
#pragma unroll
    for (int mi = 0; mi < 8; mi++)
        af[mi] = *(const short8*)&Ab[(wm * 128 + mi * 16 + l16) * 32 + quad * 8];
#pragma unroll
    for (int ni = 0; ni < 4; ni++)
        bfr[ni] = *(const short8*)&Bb[(wn * 64 + ni * 16 + l16) * 32 + quad * 8];
    __builtin_amdgcn_s_setprio(1);
#pragma unroll
    for (int mi = 0; mi < 8; mi++)
#pragma unroll
        for (int ni = 0; ni < 4; ni++)
            acc[mi][ni] = __builtin_amdgcn_mfma_f32_16x16x32_bf16(
                af[mi], bfr[ni], acc[mi][ni], 0, 0, 0);
    __builtin_amdgcn_s_setprio(0);
}

#define PHASE_END(VMSTR)                               \
    asm volatile("s_waitcnt " VMSTR ::: "memory");     \
    __builtin_amdgcn_s_barrier();                      \
    __builtin_amdgcn_sched_barrier(0);

// EPI==1: QKV epilogue (RoPE on q/k, scale folded into q, (B,T,512) bf16 stores)
// EPI==0: plain fp32 store, N=512
template <int EPI>
__global__ __launch_bounds__(512, 2) void gemm_bt(
    const ushort_t* __restrict__ A, const ushort_t* __restrict__ Bw,
    float* __restrict__ Cf,
    ushort_t* __restrict__ qout, ushort_t* __restrict__ kout, ushort_t* __restrict__ vout,
    const float* __restrict__ cosT, const float* __restrict__ sinT)
{
    __shared__ __align__(16) ushort_t As[4 * 8192];   // 4 ring slots x 256x32 bf16 = 64 KiB
    __shared__ __align__(16) ushort_t Bs[4 * 8192];   // 64 KiB
    const int bn = blockIdx.x, bm = blockIdx.y;       // bn fastest: 6 blocks share A panel
    const int tid = threadIdx.x;
    const int lane = tid & 63, wave = tid >> 6;
    const int wm = wave >> 2, wn = wave & 3;          // 2 x 4 wave grid, each owns 128x64 of C
    const int quad = lane >> 4, l16 = lane & 15;

    const ushort_t* Ag = A + (size_t)bm * 256 * KDIM;
    const ushort_t* Bg = Bw + (size_t)bn * 256 * KDIM;

    floatx4 acc[8][4] = {};

    // prologue: stage K-tiles 0,1,2 (12 loads in flight), wait tile 0 (leave 8)
    stage_tile(Ag, Bg, As, Bs, 0, tid);
    stage_tile(Ag, Bg, As + 8192, Bs + 8192, 32, tid);
    stage_tile(Ag, Bg, As + 16384, Bs + 16384, 64, tid);
    PHASE_END("vmcnt(8)")

    // main loop: K=512 -> 16 K-tiles; steady state keeps tiles t+2,t+3 in flight
#pragma unroll 1
    for (int t = 0; t < 13; t++) {
        const int pb = (t + 3) & 3;
        stage_tile(Ag, Bg, As + pb * 8192, Bs + pb * 8192, (t + 3) * 32, tid);
        compute_tile(As + (t & 3) * 8192, Bs + (t & 3) * 8192, acc, wm, wn, l16, quad);
        PHASE_END("vmcnt(8)")
    }
    // tail: tiles 13,14,15 (no more stages; drain 4, then 0)
    compute_tile(As + 1 * 8192, Bs + 1 * 8192, acc, wm, wn, l16, quad);
    PHASE_END("vmcnt(4)")
    compute_tile(As + 2 * 8192, Bs + 2 * 8192, acc, wm, wn, l16, quad);
    PHASE_END("vmcnt(0)")
    compute_tile(As + 3 * 8192, Bs + 3 * 8192, acc, wm, wn, l16, quad);

    if constexpr (EPI == 1) {
        const int n_base = bn * 256 + wn * 64;
        const int qkv = n_base >> 9;             // uniform per block (256 | 512)
        ushort_t* dst = (qkv == 0) ? qout : (qkv == 1 ? kout : vout);
#pragma unroll
        for (int mi = 0; mi < 8; mi++) {
            const int m = bm * 256 + wm * 128 + mi * 16 + quad * 4;
#pragma unroll
            for (int ni = 0; ni < 4; ni++) {
                const int n = n_base + ni * 16 + l16;
                const int nw = n & 511, hd = n & 63;
#pragma unroll
                for (int r = 0; r < 4; r++) {
                    const int mm = m + r, tt = mm & 255;
                    const size_t dsti = (size_t)mm * 512 + nw;  // (b*256+t)*512 + h*64+hd
                    float val = acc[mi][ni][r];
                    if (qkv == 2) {
                        dst[dsti] = f2bf(val);
                    } else {
                        float partner = __shfl_xor(val, 1);
                        float c = cosT[tt * 64 + hd], s = sinT[tt * 64 + hd];
                        float o = val * c + ((hd & 1) ? partner : -partner) * s;
                        dst[dsti] = (qkv == 0) ? f2bf(o * 0.125f) : f2bf(o);
                    }
                }
            }
        }
    } else {
#pragma unroll
        for (int mi = 0; mi < 8; mi++) {
            const int m = bm * 256 + wm * 128 + mi * 16 + quad * 4;
#pragma unroll
            for (int ni = 0; ni < 4; ni++) {
                const int n = bn * 256 + wn * 64 + ni * 16 + l16;
#pragma unroll
                for (int r = 0; r < 4; r++)
                    Cf[(size_t)(m + r) * 512 + n] = acc[mi][ni][r];
            }
        }
    }
}

// ---------------- flash attention: fixed m=0 (scores O(1) in fp32), deferred l reduce ----
// Q/K/V are (B,T,512); head h is a 64-col slice. 1 block per (b,h,qt).
__global__ __launch_bounds__(256) void attn_k(
    const ushort_t* __restrict__ qb, const ushort_t* __restrict__ kb,
    const ushort_t* __restrict__ vb, ushort_t* __restrict__ attb)
{
    __shared__ __align__(16) ushort_t Ks[256 * 72];
    __shared__ __align__(16) ushort_t Vt[64 * 264];
    __shared__ __align__(16) ushort_t Ps[4 * 32 * 40];

    const int blk = blockIdx.x;
    const int qt = blk & 1, bh = blk >> 1;
    const int b = bh >> 3, h = bh & 7;
    const int tid = threadIdx.x, lane = tid & 63, w = tid >> 6;
    const int quad = lane >> 4, l16 = lane & 15;
    const int q0 = qt * 128;
    const int kend = q0 + 128;

    const ushort_t* Kg = kb + ((size_t)b * 256) * 512 + h * 64;
    const ushort_t* Vg = vb + ((size_t)b * 256) * 512 + h * 64;
    const ushort_t* Qg = qb + ((size_t)b * 256) * 512 + h * 64;

    for (int e8 = tid; e8 < kend * 8; e8 += 256) {
        int t = e8 >> 3, c = (e8 & 7) << 3;
        *(short8*)&Ks[t * 72 + c] = *(const short8*)&Kg[t * 512 + c];
        short8 vv = *(const short8*)&Vg[t * 512 + c];
#pragma unroll
        for (int j = 0; j < 8; j++) Vt[(c + j) * 264 + t] = ((const ushort_t*)&vv)[j];
    }
    __syncthreads();

    short8 qf[2][2];
#pragma unroll
    for (int mi = 0; mi < 2; mi++)
#pragma unroll
        for (int kk = 0; kk < 2; kk++)
            qf[mi][kk] = *(const short8*)&Qg[(size_t)(q0 + w * 32 + mi * 16 + l16) * 512 + kk * 32 + quad * 8];

    float lsum[2][4] = {};
    floatx4 o_[2][4] = {};

    ushort_t* Pw = &Ps[w * 32 * 40];
    const int ktdiag = qt * 4 + w;      // first kt needing causal masks

    for (int kt = 0; kt <= ktdiag; kt++) {
        const bool diag = (kt == ktdiag);
        floatx4 s_[2][2] = {};
#pragma unroll
        for (int kk = 0; kk < 2; kk++) {
            short8 kf0 = *(const short8*)&Ks[(kt * 32 + l16) * 72 + kk * 32 + quad * 8];
            short8 kf1 = *(const short8*)&Ks[(kt * 32 + 16 + l16) * 72 + kk * 32 + quad * 8];
#pragma unroll
            for (int mi = 0; mi < 2; mi++) {
                s_[mi][0] = __builtin_amdgcn_mfma_f32_16x16x32_bf16(qf[mi][kk], kf0, s_[mi][0], 0, 0, 0);
                s_[mi][1] = __builtin_amdgcn_mfma_f32_16x16x32_bf16(qf[mi][kk], kf1, s_[mi][1], 0, 0, 0);
            }
        }
#pragma unroll
        for (int mi = 0; mi < 2; mi++) {
#pragma unroll
            for (int r = 0; r < 4; r++) {
                float p0 = exp2f(s_[mi][0][r] * LOG2E);
                float p1 = exp2f(s_[mi][1][r] * LOG2E);
                if (diag) {
                    const int rl = mi * 16 + quad * 4 + r;   // row - kt*32
                    if (l16 > rl)      p0 = 0.f;
                    if (l16 + 16 > rl) p1 = 0.f;
                }
                lsum[mi][r] += p0 + p1;
                const int rowL = mi * 16 + quad * 4 + r;
                Pw[rowL * 40 + l16] = f2bf(p0);
                Pw[rowL * 40 + 16 + l16] = f2bf(p1);
            }
        }
        __asm__ volatile("s_waitcnt lgkmcnt(0)" ::: "memory");
        short8 pf[2];
#pragma unroll
        for (int mi = 0; mi < 2; mi++)
            pf[mi] = *(const short8*)&Pw[(mi * 16 + l16) * 40 + quad * 8];
#pragma unroll
        for (int vni = 0; vni < 4; vni++) {
            short8 vf = *(const short8*)&Vt[(vni * 16 + l16) * 264 + kt * 32 + quad * 8];
#pragma unroll
            for (int mi = 0; mi < 2; mi++)
                o_[mi][vni] = __builtin_amdgcn_mfma_f32_16x16x32_bf16(pf[mi], vf, o_[mi][vni], 0, 0, 0);
        }
    }

#pragma unroll
    for (int mi = 0; mi < 2; mi++) {
#pragma unroll
        for (int r = 0; r < 4; r++) {
            float rs = lsum[mi][r];
            rs += __shfl_xor(rs, 1);
            rs += __shfl_xor(rs, 2);
            rs += __shfl_xor(rs, 4);
            rs += __shfl_xor(rs, 8);
            const float inv = 1.f / rs;
            const int t = q0 + w * 32 + mi * 16 + quad * 4 + r;
            const size_t base = ((size_t)(b * 256 + t)) * 512 + h * 64;
#pragma unroll
            for (int vni = 0; vni < 4; vni++)
                attb[base + vni * 16 + l16] = f2bf(o_[mi][vni][r] * inv);
        }
    }
}

extern "C" void kernel_launch(void* const* d_in, const int* in_sizes, int n_in,
                              void* d_out, int out_size, void* d_ws, size_t ws_size,
                              hipStream_t stream) {
    const float* x    = (const float*)d_in[0];
    const float* cosT = (const float*)d_in[1];
    const float* sinT = (const float*)d_in[2];
    const float* wqkv = (const float*)d_in[3];
    const float* wout = (const float*)d_in[4];
    float* out = (float*)d_out;
    ushort_t* ws = (ushort_t*)d_ws;

    ushort_t* xb    = ws + XB_OFF;
    ushort_t* wqkvb = ws + WQKV_OFF;
    ushort_t* woutb = ws + WOUT_OFF;
    ushort_t* qbp   = ws + QB_OFF;
    ushort_t* kbp   = ws + KB_OFF;
    ushort_t* vbp   = ws + VB_OFF;
    ushort_t* attb  = ws + ATT_OFF;

    convert_k<<<33792, 256, 0, stream>>>(x, wqkv, wout, ws);
    gemm_bt<1><<<dim3(6, 256), 512, 0, stream>>>(xb, wqkvb, nullptr, qbp, kbp, vbp, cosT, sinT);
    attn_k<<<4096, 256, 0, stream>>>(qbp, kbp, vbp, attb);
    gemm_bt<0><<<dim3(2, 256), 512, 0, stream>>>(attb, woutb, out, nullptr, nullptr, nullptr, nullptr, nullptr);
}

// Round 3
// 641.885 us; speedup vs baseline: 1.0319x; 1.0319x over previous
//
#include <hip/hip_runtime.h>

typedef float floatx4 __attribute__((ext_vector_type(4)));
typedef short short8 __attribute__((ext_vector_type(8)));
typedef unsigned short ushort_t;

#define AS1 __attribute__((address_space(1)))
#define AS3 __attribute__((address_space(3)))

__device__ __forceinline__ void gload_lds16(const ushort_t* g, ushort_t* l) {
    __builtin_amdgcn_global_load_lds((const AS1 unsigned int*)g, (AS3 unsigned int*)l, 16, 0, 0);
}

__device__ __forceinline__ ushort_t f2bf(float f) {
    union { float f; unsigned u; } v; v.f = f;
    unsigned r = v.u + 0x7FFFu + ((v.u >> 16) & 1u);
    return (ushort_t)(r >> 16);
}

#define KDIM 512
#define LOG2E 1.44269504f
// rule 18: sched_barrier(0) right after inline-asm lgkmcnt(0)
#define LGKM0 do { asm volatile("s_waitcnt lgkmcnt(0)" ::: "memory"); __builtin_amdgcn_sched_barrier(0); } while (0)

// ws element offsets (bf16 elems). attb reuses xb's region (xb dead after GEMM1).
#define XB_OFF   0ull
#define ATT_OFF  0ull
#define WQKV_OFF 33554432ull
#define WOUT_OFF 34340864ull
#define QB_OFF   34603008ull
#define KB_OFF   68157440ull
#define VB_OFF   101711872ull

// ---------------- convert fp32 -> bf16 (x, Wqkv, Wout concatenated) ----------------
__global__ __launch_bounds__(256) void convert_k(
    const float* __restrict__ x, const float* __restrict__ wqkv,
    const float* __restrict__ wout, ushort_t* __restrict__ dst)
{
    size_t i = (size_t)blockIdx.x * 256 + threadIdx.x;
    size_t e = i * 4;
    const float* s; size_t o;
    if (e < 33554432ull)      { s = x;    o = e; }
    else if (e < 34340864ull) { s = wqkv; o = e - 33554432ull; }
    else                      { s = wout; o = e - 34340864ull; }
    float4 v = *(const float4*)(s + o);
    ushort4 r;
    r.x = f2bf(v.x); r.y = f2bf(v.y); r.z = f2bf(v.z); r.w = f2bf(v.w);
    *(ushort4*)(dst + e) = r;
}

// ---------------- GEMM C = A(MxK) * B(NxK)^T, bf16 MFMA ----------------
// m201-style 8-phase template: 256x256 tile, 512 thr (8 waves 2Mx4N), BK=64,
// LDS [2 dbuf][2 K-half] x 256x32 per matrix (K-half split => dead-slot restage),
// 2 barriers/phase, lgkmcnt(0)+sched_barrier, setprio around 16-MFMA cluster,
// 1 half-tile staged per phase, vmcnt(6) once per K-tile (3 halves in flight).
// 64B LDS rows => frag ds_read_b128 conflict-free without swizzle (gload_lds legal).

// stage one half-tile (256 rows x 32 K-cols, 16 KiB) of A or B into LDS slot L
__device__ __forceinline__ void stage_half(const ushort_t* __restrict__ G,
    ushort_t* L, int u, int kh, int tid)
{
    const int c0 = u * 64 + kh * 32;
#pragma unroll
    for (int rnd = 0; rnd < 2; rnd++) {
        const int e = rnd * 512 + tid;           // 8-elem chunk id in [0,1024)
        const int row = e >> 2, c8 = (e & 3) << 3;
        gload_lds16(G + (size_t)row * KDIM + c0 + c8, L + e * 8);  // dest = base + lane*16B
    }
}

// EPI==1: QKV epilogue (RoPE, scale folded into q, LDS-transposed 16B stores)
// EPI==0: plain fp32 store, N=512
template <int EPI>
__global__ __launch_bounds__(512, 2) void gemm_bt(
    const ushort_t* __restrict__ A, const ushort_t* __restrict__ Bw,
    float* __restrict__ Cf,
    ushort_t* __restrict__ qout, ushort_t* __restrict__ kout, ushort_t* __restrict__ vout,
    const float* __restrict__ cosT, const float* __restrict__ sinT)
{
    __shared__ __align__(16) ushort_t As[2 * 2 * 8192];   // [db][kh][256*32] = 64 KiB
    __shared__ __align__(16) ushort_t Bs[2 * 2 * 8192];   // 64 KiB
    const int bn = blockIdx.x, bm = blockIdx.y;           // bn fastest: blocks share A panel
    const int tid = threadIdx.x;
    const int lane = tid & 63, wave = tid >> 6;
    const int wm = wave >> 2, wn = wave & 3;              // wave owns 128x64 of C
    const int quad = lane >> 4, l16 = lane & 15;

    const ushort_t* Ag = A + (size_t)bm * 256 * KDIM;
    const ushort_t* Bg = Bw + (size_t)bn * 256 * KDIM;

    floatx4 acc[8][4] = {};

    // ---- prologue: K-tile 0 (4 halves), pace, 3 halves of K-tile 1 ----
    stage_half(Bg, Bs + 0,     0, 0, tid);                // BK0(0)
    stage_half(Ag, As + 0,     0, 0, tid);                // AK0(0)
    stage_half(Bg, Bs + 8192,  0, 1, tid);                // BK1(0)
    stage_half(Ag, As + 8192,  0, 1, tid);                // AK1(0)
    asm volatile("s_waitcnt vmcnt(4)" ::: "memory");
    stage_half(Bg, Bs + 16384,        1, 0, tid);         // BK0(1)
    stage_half(Ag, As + 16384,        1, 0, tid);         // AK0(1)
    stage_half(Bg, Bs + 16384 + 8192, 1, 1, tid);         // BK1(1)
    asm volatile("s_waitcnt vmcnt(6)" ::: "memory");      // K-tile 0 resident
    __builtin_amdgcn_s_barrier();

    // mode: 0 = steady (all stages, vmcnt6), 1 = u==NT-2 (q1 stage only, vmcnt0), 2 = last
    auto ktile_body = [&](int u, int mode) {
        const int db = u & 1;
        const ushort_t* A0 = As + db * 16384;
        const ushort_t* A1 = A0 + 8192;
        const ushort_t* B0 = Bs + db * 16384;
        const ushort_t* B1 = B0 + 8192;
        short8 af[4], bfr[4];

        // q1: kk0, mi 0-3 (8 reads) | stage AK1(u+1) into other dbuf
#pragma unroll
        for (int i = 0; i < 4; i++)
            af[i] = *(const short8*)&A0[(wm * 128 + i * 16 + l16) * 32 + quad * 8];
#pragma unroll
        for (int j = 0; j < 4; j++)
            bfr[j] = *(const short8*)&B0[(wn * 64 + j * 16 + l16) * 32 + quad * 8];
        if (mode < 2) stage_half(Ag, As + ((u + 1) & 1) * 16384 + 8192, u + 1, 1, tid);
        __builtin_amdgcn_s_barrier();
        LGKM0;
        __builtin_amdgcn_s_setprio(1);
#pragma unroll
        for (int i = 0; i < 4; i++)
#pragma unroll
            for (int j = 0; j < 4; j++)
                acc[i][j] = __builtin_amdgcn_mfma_f32_16x16x32_bf16(af[i], bfr[j], acc[i][j], 0, 0, 0);
        __builtin_amdgcn_s_setprio(0);
        __builtin_amdgcn_s_barrier();

        // q2: kk0, mi 4-7 (4 reads, bfr reused) | stage BK0(u+2) (BK0(u) dead after q1)
#pragma unroll
        for (int i = 0; i < 4; i++)
            af[i] = *(const short8*)&A0[(wm * 128 + (4 + i) * 16 + l16) * 32 + quad * 8];
        if (mode == 0) stage_half(Bg, Bs + db * 16384, u + 2, 0, tid);
        __builtin_amdgcn_s_barrier();
        LGKM0;
        __builtin_amdgcn_s_setprio(1);
#pragma unroll
        for (int i = 0; i < 4; i++)
#pragma unroll
            for (int j = 0; j < 4; j++)
                acc[4 + i][j] = __builtin_amdgcn_mfma_f32_16x16x32_bf16(af[i], bfr[j], acc[4 + i][j], 0, 0, 0);
        __builtin_amdgcn_s_setprio(0);
        __builtin_amdgcn_s_barrier();

        // q3: kk1, mi 0-3 (8 reads) | stage AK0(u+2) (AK0(u) dead after q2)
#pragma unroll
        for (int i = 0; i < 4; i++)
            af[i] = *(const short8*)&A1[(wm * 128 + i * 16 + l16) * 32 + quad * 8];
#pragma unroll
        for (int j = 0; j < 4; j++)
            bfr[j] = *(const short8*)&B1[(wn * 64 + j * 16 + l16) * 32 + quad * 8];
        if (mode == 0) stage_half(Ag, As + db * 16384, u + 2, 0, tid);
        __builtin_amdgcn_s_barrier();
        LGKM0;
        __builtin_amdgcn_s_setprio(1);
#pragma unroll
        for (int i = 0; i < 4; i++)
#pragma unroll
            for (int j = 0; j < 4; j++)
                acc[i][j] = __builtin_amdgcn_mfma_f32_16x16x32_bf16(af[i], bfr[j], acc[i][j], 0, 0, 0);
        __builtin_amdgcn_s_setprio(0);
        __builtin_amdgcn_s_barrier();

        // q4: kk1, mi 4-7 (4 reads) | stage BK1(u+2) (BK1(u) dead after q3) | vmcnt
#pragma unroll
        for (int i = 0; i < 4; i++)
            af[i] = *(const short8*)&A1[(wm * 128 + (4 + i) * 16 + l16) * 32 + quad * 8];
        if (mode == 0) stage_half(Bg, Bs + db * 16384 + 8192, u + 2, 1, tid);
        __builtin_amdgcn_s_barrier();
        LGKM0;
        __builtin_amdgcn_s_setprio(1);
#pragma unroll
        for (int i = 0; i < 4; i++)
#pragma unroll
            for (int j = 0; j < 4; j++)
                acc[4 + i][j] = __builtin_amdgcn_mfma_f32_16x16x32_bf16(af[i], bfr[j], acc[4 + i][j], 0, 0, 0);
        __builtin_amdgcn_s_setprio(0);
        if (mode == 0)      { asm volatile("s_waitcnt vmcnt(6)" ::: "memory"); }
        else if (mode == 1) { asm volatile("s_waitcnt vmcnt(0)" ::: "memory"); }
        __builtin_amdgcn_s_barrier();
    };

    // K = 512 -> 8 K-tiles
#pragma unroll 1
    for (int u = 0; u < 6; u++) ktile_body(u, 0);
    ktile_body(6, 1);
    ktile_body(7, 2);

    if constexpr (EPI == 1) {
        // RoPE into per-wave 16 KiB LDS tile (XOR-swizzled), then 128B-line stores.
        const int n_base = bn * 256 + wn * 64;
        const int qkv = n_base >> 9;             // uniform per wave (64-col slice never straddles 512)
        ushort_t* dst = (qkv == 0) ? qout : (qkv == 1 ? kout : vout);
        ushort_t* Ep = (wave < 4) ? (As + wave * 8192) : (Bs + (wave - 4) * 8192);
#pragma unroll
        for (int mi = 0; mi < 8; mi++) {
#pragma unroll
            for (int ni = 0; ni < 4; ni++) {
#pragma unroll
                for (int r = 0; r < 4; r++) {
                    const int row = mi * 16 + quad * 4 + r;      // 0..127 in wave tile
                    const int m = bm * 256 + wm * 128 + row;
                    const int tt = m & 255;
                    const int n = n_base + ni * 16 + l16;
                    const int hd = n & 63;
                    float val = acc[mi][ni][r];
                    float o;
                    if (qkv == 2) {
                        o = val;
                    } else {
                        float partner = __shfl_xor(val, 1);
                        float c = cosT[tt * 64 + hd], s = sinT[tt * 64 + hd];
                        o = val * c + ((hd & 1) ? partner : -partner) * s;
                        if (qkv == 0) o *= 0.125f;
                    }
                    const int colp = (ni * 16 + l16) ^ (((row >> 2) & 3) << 4);  // = ^(quad<<4)
                    Ep[row * 64 + colp] = f2bf(o);
                }
            }
        }
        LGKM0;   // per-wave ds_write -> ds_read ordering (Ep is wave-private)
#pragma unroll
        for (int t = 0; t < 16; t++) {
            const int row = t * 8 + (lane >> 3);
            const int c0 = (lane & 7) * 8;
            const int colp = c0 ^ (((row >> 2) & 3) << 4);
            short8 v = *(const short8*)&Ep[row * 64 + colp];
            const int m = bm * 256 + wm * 128 + row;
            *(short8*)&dst[(size_t)m * 512 + (n_base & 511) + c0] = v;
        }
    } else {
#pragma unroll
        for (int mi = 0; mi < 8; mi++) {
            const int m = bm * 256 + wm * 128 + mi * 16 + quad * 4;
#pragma unroll
            for (int ni = 0; ni < 4; ni++) {
                const int n = bn * 256 + wn * 64 + ni * 16 + l16;
#pragma unroll
                for (int r = 0; r < 4; r++)
                    Cf[(size_t)(m + r) * 512 + n] = acc[mi][ni][r];
            }
        }
    }
}

// ---------------- flash attention: fixed m=0 (scores O(1) in fp32), deferred l reduce ----
__global__ __launch_bounds__(256) void attn_k(
    const ushort_t* __restrict__ qb, const ushort_t* __restrict__ kb,
    const ushort_t* __restrict__ vb, ushort_t* __restrict__ attb)
{
    __shared__ __align__(16) ushort_t Ks[256 * 72];
    __shared__ __align__(16) ushort_t Vt[64 * 264];
    __shared__ __align__(16) ushort_t Ps[4 * 32 * 40];

    const int blk = blockIdx.x;
    const int qt = blk & 1, bh = blk >> 1;
    const int b = bh >> 3, h = bh & 7;
    const int tid = threadIdx.x, lane = tid & 63, w = tid >> 6;
    const int quad = lane >> 4, l16 = lane & 15;
    const int q0 = qt * 128;
    const int kend = q0 + 128;

    const ushort_t* Kg = kb + ((size_t)b * 256) * 512 + h * 64;
    const ushort_t* Vg = vb + ((size_t)b * 256) * 512 + h * 64;
    const ushort_t* Qg = qb + ((size_t)b * 256) * 512 + h * 64;

    for (int e8 = tid; e8 < kend * 8; e8 += 256) {
        int t = e8 >> 3, c = (e8 & 7) << 3;
        *(short8*)&Ks[t * 72 + c] = *(const short8*)&Kg[t * 512 + c];
        short8 vv = *(const short8*)&Vg[t * 512 + c];
#pragma unroll
        for (int j = 0; j < 8; j++) Vt[(c + j) * 264 + t] = ((const ushort_t*)&vv)[j];
    }
    __syncthreads();

    short8 qf[2][2];
#pragma unroll
    for (int mi = 0; mi < 2; mi++)
#pragma unroll
        for (int kk = 0; kk < 2; kk++)
            qf[mi][kk] = *(const short8*)&Qg[(size_t)(q0 + w * 32 + mi * 16 + l16) * 512 + kk * 32 + quad * 8];

    float lsum[2][4] = {};
    floatx4 o_[2][4] = {};

    ushort_t* Pw = &Ps[w * 32 * 40];
    const int ktdiag = qt * 4 + w;

    for (int kt = 0; kt <= ktdiag; kt++) {
        const bool diag = (kt == ktdiag);
        floatx4 s_[2][2] = {};
#pragma unroll
        for (int kk = 0; kk < 2; kk++) {
            short8 kf0 = *(const short8*)&Ks[(kt * 32 + l16) * 72 + kk * 32 + quad * 8];
            short8 kf1 = *(const short8*)&Ks[(kt * 32 + 16 + l16) * 72 + kk * 32 + quad * 8];
#pragma unroll
            for (int mi = 0; mi < 2; mi++) {
                s_[mi][0] = __builtin_amdgcn_mfma_f32_16x16x32_bf16(qf[mi][kk], kf0, s_[mi][0], 0, 0, 0);
                s_[mi][1] = __builtin_amdgcn_mfma_f32_16x16x32_bf16(qf[mi][kk], kf1, s_[mi][1], 0, 0, 0);
            }
        }
#pragma unroll
        for (int mi = 0; mi < 2; mi++) {
#pragma unroll
            for (int r = 0; r < 4; r++) {
                float p0 = exp2f(s_[mi][0][r] * LOG2E);
                float p1 = exp2f(s_[mi][1][r] * LOG2E);
                if (diag) {
                    const int rl = mi * 16 + quad * 4 + r;
                    if (l16 > rl)      p0 = 0.f;
                    if (l16 + 16 > rl) p1 = 0.f;
                }
                lsum[mi][r] += p0 + p1;
                const int rowL = mi * 16 + quad * 4 + r;
                Pw[rowL * 40 + l16] = f2bf(p0);
                Pw[rowL * 40 + 16 + l16] = f2bf(p1);
            }
        }
        __asm__ volatile("s_waitcnt lgkmcnt(0)" ::: "memory");
        short8 pf[2];
#pragma unroll
        for (int mi = 0; mi < 2; mi++)
            pf[mi] = *(const short8*)&Pw[(mi * 16 + l16) * 40 + quad * 8];
#pragma unroll
        for (int vni = 0; vni < 4; vni++) {
            short8 vf = *(const short8*)&Vt[(vni * 16 + l16) * 264 + kt * 32 + quad * 8];
#pragma unroll
            for (int mi = 0; mi < 2; mi++)
                o_[mi][vni] = __builtin_amdgcn_mfma_f32_16x16x32_bf16(pf[mi], vf, o_[mi][vni], 0, 0, 0);
        }
    }

#pragma unroll
    for (int mi = 0; mi < 2; mi++) {
#pragma unroll
        for (int r = 0; r < 4; r++) {
            float rs = lsum[mi][r];
            rs += __shfl_xor(rs, 1);
            rs += __shfl_xor(rs, 2);
            rs += __shfl_xor(rs, 4);
            rs += __shfl_xor(rs, 8);
            const float inv = 1.f / rs;
            const int t = q0 + w * 32 + mi * 16 + quad * 4 + r;
            const size_t base = ((size_t)(b * 256 + t)) * 512 + h * 64;
#pragma unroll
            for (int vni = 0; vni < 4; vni++)
                attb[base + vni * 16 + l16] = f2bf(o_[mi][vni][r] * inv);
        }
    }
}

extern "C" void kernel_launch(void* const* d_in, const int* in_sizes, int n_in,
                              void* d_out, int out_size, void* d_ws, size_t ws_size,
                              hipStream_t stream) {
    const float* x    = (const float*)d_in[0];
    const float* cosT = (const float*)d_in[1];
    const float* sinT = (const float*)d_in[2];
    const float* wqkv = (const float*)d_in[3];
    const float* wout = (const float*)d_in[4];
    float* out = (float*)d_out;
    ushort_t* ws = (ushort_t*)d_ws;

    ushort_t* xb    = ws + XB_OFF;
    ushort_t* wqkvb = ws + WQKV_OFF;
    ushort_t* woutb = ws + WOUT_OFF;
    ushort_t* qbp   = ws + QB_OFF;
    ushort_t* kbp   = ws + KB_OFF;
    ushort_t* vbp   = ws + VB_OFF;
    ushort_t* attb  = ws + ATT_OFF;

    convert_k<<<33792, 256, 0, stream>>>(x, wqkv, wout, ws);
    gemm_bt<1><<<dim3(6, 256), 512, 0, stream>>>(xb, wqkvb, nullptr, qbp, kbp, vbp, cosT, sinT);
    attn_k<<<4096, 256, 0, stream>>>(qbp, kbp, vbp, attb);
    gemm_bt<0><<<dim3(2, 256), 512, 0, stream>>>(attb, woutb, out, nullptr, nullptr, nullptr, nullptr, nullptr);
}

// Round 4
// 543.354 us; speedup vs baseline: 1.2191x; 1.1813x over previous
//
#include <hip/hip_runtime.h>

typedef float floatx4 __attribute__((ext_vector_type(4)));
typedef short short8 __attribute__((ext_vector_type(8)));
typedef unsigned short ushort_t;

#define AS1 __attribute__((address_space(1)))
#define AS3 __attribute__((address_space(3)))

__device__ __forceinline__ void gload_lds16(const ushort_t* g, ushort_t* l) {
    __builtin_amdgcn_global_load_lds((const AS1 unsigned int*)g, (AS3 unsigned int*)l, 16, 0, 0);
}

__device__ __forceinline__ ushort_t f2bf(float f) {
    union { float f; unsigned u; } v; v.f = f;
    unsigned r = v.u + 0x7FFFu + ((v.u >> 16) & 1u);
    return (ushort_t)(r >> 16);
}

#define KDIM 512
#define LOG2E 1.44269504f
// rule 18: sched_barrier(0) right after inline-asm lgkmcnt(0)
#define LGKM0 do { asm volatile("s_waitcnt lgkmcnt(0)" ::: "memory"); __builtin_amdgcn_sched_barrier(0); } while (0)

// ws element offsets (bf16 elems). attb reuses xb's region (xb dead after GEMM1).
#define XB_OFF   0ull
#define ATT_OFF  0ull
#define WQKV_OFF 33554432ull
#define WOUT_OFF 34340864ull
#define QB_OFF   34603008ull
#define KB_OFF   68157440ull
#define VB_OFF   101711872ull

// ---------------- convert fp32 -> bf16 (x, Wqkv, Wout concatenated) ----------------
__global__ __launch_bounds__(256) void convert_k(
    const float* __restrict__ x, const float* __restrict__ wqkv,
    const float* __restrict__ wout, ushort_t* __restrict__ dst)
{
    size_t i = (size_t)blockIdx.x * 256 + threadIdx.x;
    size_t e = i * 4;
    const float* s; size_t o;
    if (e < 33554432ull)      { s = x;    o = e; }
    else if (e < 34340864ull) { s = wqkv; o = e - 33554432ull; }
    else                      { s = wout; o = e - 34340864ull; }
    float4 v = *(const float4*)(s + o);
    ushort4 r;
    r.x = f2bf(v.x); r.y = f2bf(v.y); r.z = f2bf(v.z); r.w = f2bf(v.w);
    *(ushort4*)(dst + e) = r;
}

// ---------------- GEMM C = A(MxK) * B(NxK)^T, bf16 MFMA, 128x128 tile, BK=64 ----------------
// Round-0 K-loop structure (known-good: 3 blk/CU, simple stage/sync/compute/sync), plus:
//  (G1) LDS [kh][128][32]: 64B rows -> frag ds_read_b128 avoids the 16-way conflict
//       of 128B rows (R0's 3.8e7 SQ_LDS_BANK_CONFLICT signature).
//  (G2) bijective XCD remap: blocks f with f%8==x run on XCD x (round-robin dispatch);
//       give XCD x the contiguous bm chunk [64x,64x+64), bn-fastest, so all NBN blocks
//       sharing an A panel hit one L2 (8 panels x 128KB + B fully resident < 4MB).
//  (G3) EPI=1 epilogue via per-wave LDS tile -> full 128B-line stores (kills the
//       write-allocate over-fetch measured in R0: FETCH 267MB vs 66MB input).
template <int EPI>
__global__ __launch_bounds__(256, 3) void gemm_bt(
    const ushort_t* __restrict__ A, const ushort_t* __restrict__ Bw,
    float* __restrict__ Cf,
    ushort_t* __restrict__ qout, ushort_t* __restrict__ kout, ushort_t* __restrict__ vout,
    const float* __restrict__ cosT, const float* __restrict__ sinT)
{
    __shared__ __align__(16) ushort_t As[2 * 128 * 32];   // [kh][row][32], 16 KB
    __shared__ __align__(16) ushort_t Bs[2 * 128 * 32];   // 16 KB
    constexpr int NBN = (EPI == 1) ? 12 : 4;              // N blocks: 1536/128 or 512/128
    const int f = blockIdx.x;
    const int wkr = (f & 7) * (NBN * 64) + (f >> 3);      // grid = NBN*512, divisible by 8
    const int bm = wkr / NBN, bn = wkr % NBN;
    const int tid = threadIdx.x;
    const int lane = tid & 63, wave = tid >> 6;
    const int wm = wave & 1, wn = wave >> 1;              // 2x2 waves, each owns 64x64 of C
    const int quad = lane >> 4, l16 = lane & 15;

    const ushort_t* Ag = A + (size_t)bm * 128 * KDIM;
    const ushort_t* Bg = Bw + (size_t)bn * 128 * KDIM;

    floatx4 acc[4][4] = {};

    for (int k0 = 0; k0 < KDIM; k0 += 64) {
#pragma unroll
        for (int it = 0; it < 4; it++) {
            const int e = it * 256 + tid;                 // chunk id [0,1024), kh uniform per it
            const int kh = e >> 9, rem = e & 511;
            const int row = rem >> 2, c8 = (rem & 3) << 3;
            gload_lds16(Ag + row * KDIM + k0 + kh * 32 + c8, &As[e * 8]);
            gload_lds16(Bg + row * KDIM + k0 + kh * 32 + c8, &Bs[e * 8]);
        }
        __syncthreads();
#pragma unroll
        for (int kh = 0; kh < 2; kh++) {
            short8 af[4], bf[4];
#pragma unroll
            for (int mi = 0; mi < 4; mi++)
                af[mi] = *(const short8*)&As[kh * 4096 + (wm * 64 + mi * 16 + l16) * 32 + quad * 8];
#pragma unroll
            for (int ni = 0; ni < 4; ni++)
                bf[ni] = *(const short8*)&Bs[kh * 4096 + (wn * 64 + ni * 16 + l16) * 32 + quad * 8];
#pragma unroll
            for (int mi = 0; mi < 4; mi++)
#pragma unroll
                for (int ni = 0; ni < 4; ni++)
                    acc[mi][ni] = __builtin_amdgcn_mfma_f32_16x16x32_bf16(
                        af[mi], bf[ni], acc[mi][ni], 0, 0, 0);
        }
        __syncthreads();
    }

    if constexpr (EPI == 1) {
        // RoPE into per-wave 8KB LDS tile [64][64] (quad-XOR swizzle), then 128B-line stores.
        const int n_base = bn * 128 + wn * 64;
        const int qkv = n_base >> 9;                      // uniform per wave (64 | 512)
        ushort_t* dst = (qkv == 0) ? qout : (qkv == 1 ? kout : vout);
        ushort_t* Ep = (wave < 2) ? (As + wave * 4096) : (Bs + (wave - 2) * 4096);
        const int nb = n_base & 511;
#pragma unroll
        for (int mi = 0; mi < 4; mi++) {
#pragma unroll
            for (int ni = 0; ni < 4; ni++) {
#pragma unroll
                for (int r = 0; r < 4; r++) {
                    const int row = mi * 16 + quad * 4 + r;   // 0..63 in wave tile
                    const int m = bm * 128 + wm * 64 + row;
                    const int tt = m & 255;
                    const int col = ni * 16 + l16;
                    const int hd = col;                        // nb is a multiple of 64
                    float val = acc[mi][ni][r];
                    float o;
                    if (qkv == 2) {
                        o = val;
                    } else {
                        float partner = __shfl_xor(val, 1);
                        float c = cosT[tt * 64 + hd], s = sinT[tt * 64 + hd];
                        o = val * c + ((hd & 1) ? partner : -partner) * s;
                        if (qkv == 0) o *= 0.125f;
                    }
                    const int colp = col ^ (quad << 4);        // (row>>2)&3 == quad here
                    Ep[row * 64 + colp] = f2bf(o);
                }
            }
        }
        LGKM0;   // Ep is wave-private: only same-wave ds_write->ds_read ordering needed
#pragma unroll
        for (int t8 = 0; t8 < 8; t8++) {
            const int row = t8 * 8 + (lane >> 3);
            const int c0 = (lane & 7) * 8;
            const int colp = c0 ^ (((row >> 2) & 3) << 4);
            short8 v = *(const short8*)&Ep[row * 64 + colp];
            const int m = bm * 128 + wm * 64 + row;
            *(short8*)&dst[(size_t)m * 512 + nb + c0] = v;    // 8 lanes = one 128B line
        }
    } else {
        // fp32 store, ni innermost so each (row) gets 4 adjacent 64B segments (L2 merges)
#pragma unroll
        for (int mi = 0; mi < 4; mi++) {
#pragma unroll
            for (int r = 0; r < 4; r++) {
                const int m = bm * 128 + wm * 64 + mi * 16 + quad * 4 + r;
#pragma unroll
                for (int ni = 0; ni < 4; ni++) {
                    const int n = bn * 128 + wn * 64 + ni * 16 + l16;
                    Cf[(size_t)m * 512 + n] = acc[mi][ni][r];
                }
            }
        }
    }
}

// ---------------- flash attention: fixed m=0 (scores O(1) in fp32), deferred l reduce ----
// Vt granule-XOR swizzle: Vt element (d,t) at d*264 + (t&7) + (((t>>3)^(d>>3))<<3).
// Fixes the staging transpose writes (row-step 8 x 132dw == 0 mod 32 -> was 8-way same-bank).
__device__ __forceinline__ int vt_addr(int d, int t) {
    return d * 264 + (t & 7) + ((((t >> 3) ^ (d >> 3)) & 31) << 3);
}

__global__ __launch_bounds__(256) void attn_k(
    const ushort_t* __restrict__ qb, const ushort_t* __restrict__ kb,
    const ushort_t* __restrict__ vb, ushort_t* __restrict__ attb)
{
    __shared__ __align__(16) ushort_t Ks[256 * 72];
    __shared__ __align__(16) ushort_t Vt[64 * 264];
    __shared__ __align__(16) ushort_t Ps[4 * 32 * 40];

    // XCD remap: the two q-tiles sharing a (b,h) KV land on the same XCD L2.
    const int f = blockIdx.x;
    const int wkr = (f & 7) * 512 + (f >> 3);
    const int qt = wkr & 1, bh = wkr >> 1;
    const int b = bh >> 3, h = bh & 7;
    const int tid = threadIdx.x, lane = tid & 63, w = tid >> 6;
    const int quad = lane >> 4, l16 = lane & 15;
    const int q0 = qt * 128;
    const int kend = q0 + 128;

    const ushort_t* Kg = kb + ((size_t)b * 256) * 512 + h * 64;
    const ushort_t* Vg = vb + ((size_t)b * 256) * 512 + h * 64;
    const ushort_t* Qg = qb + ((size_t)b * 256) * 512 + h * 64;

    for (int e8 = tid; e8 < kend * 8; e8 += 256) {
        int t = e8 >> 3, c = (e8 & 7) << 3;
        *(short8*)&Ks[t * 72 + c] = *(const short8*)&Kg[t * 512 + c];
        short8 vv = *(const short8*)&Vg[t * 512 + c];
#pragma unroll
        for (int j = 0; j < 8; j++) Vt[vt_addr(c + j, t)] = ((const ushort_t*)&vv)[j];
    }
    __syncthreads();

    short8 qf[2][2];
#pragma unroll
    for (int mi = 0; mi < 2; mi++)
#pragma unroll
        for (int kk = 0; kk < 2; kk++)
            qf[mi][kk] = *(const short8*)&Qg[(size_t)(q0 + w * 32 + mi * 16 + l16) * 512 + kk * 32 + quad * 8];

    float lsum[2][4] = {};
    floatx4 o_[2][4] = {};

    ushort_t* Pw = &Ps[w * 32 * 40];
    const int ktdiag = qt * 4 + w;      // first kt needing causal masks

    for (int kt = 0; kt <= ktdiag; kt++) {
        const bool diag = (kt == ktdiag);
        floatx4 s_[2][2] = {};
#pragma unroll
        for (int kk = 0; kk < 2; kk++) {
            short8 kf0 = *(const short8*)&Ks[(kt * 32 + l16) * 72 + kk * 32 + quad * 8];
            short8 kf1 = *(const short8*)&Ks[(kt * 32 + 16 + l16) * 72 + kk * 32 + quad * 8];
#pragma unroll
            for (int mi = 0; mi < 2; mi++) {
                s_[mi][0] = __builtin_amdgcn_mfma_f32_16x16x32_bf16(qf[mi][kk], kf0, s_[mi][0], 0, 0, 0);
                s_[mi][1] = __builtin_amdgcn_mfma_f32_16x16x32_bf16(qf[mi][kk], kf1, s_[mi][1], 0, 0, 0);
            }
        }
#pragma unroll
        for (int mi = 0; mi < 2; mi++) {
#pragma unroll
            for (int r = 0; r < 4; r++) {
                float p0 = exp2f(s_[mi][0][r] * LOG2E);
                float p1 = exp2f(s_[mi][1][r] * LOG2E);
                if (diag) {
                    const int rl = mi * 16 + quad * 4 + r;   // row - kt*32
                    if (l16 > rl)      p0 = 0.f;
                    if (l16 + 16 > rl) p1 = 0.f;
                }
                lsum[mi][r] += p0 + p1;
                const int rowL = mi * 16 + quad * 4 + r;
                Pw[rowL * 40 + l16] = f2bf(p0);
                Pw[rowL * 40 + 16 + l16] = f2bf(p1);
            }
        }
        __asm__ volatile("s_waitcnt lgkmcnt(0)" ::: "memory");
        short8 pf[2];
#pragma unroll
        for (int mi = 0; mi < 2; mi++)
            pf[mi] = *(const short8*)&Pw[(mi * 16 + l16) * 40 + quad * 8];
#pragma unroll
        for (int vni = 0; vni < 4; vni++) {
            short8 vf = *(const short8*)&Vt[vt_addr(vni * 16 + l16, kt * 32 + quad * 8)];
#pragma unroll
            for (int mi = 0; mi < 2; mi++)
                o_[mi][vni] = __builtin_amdgcn_mfma_f32_16x16x32_bf16(pf[mi], vf, o_[mi][vni], 0, 0, 0);
        }
    }

    // epilogue: per-wave LDS tile (reuse Ks, dead after the barrier) -> 128B-line stores
    __syncthreads();
    ushort_t* Ow = Ks + w * 2304;       // 32 rows x stride 72, granule-XOR swizzled
#pragma unroll
    for (int mi = 0; mi < 2; mi++) {
#pragma unroll
        for (int r = 0; r < 4; r++) {
            float rs = lsum[mi][r];
            rs += __shfl_xor(rs, 1);
            rs += __shfl_xor(rs, 2);
            rs += __shfl_xor(rs, 4);
            rs += __shfl_xor(rs, 8);
            const float inv = 1.f / rs;
            const int rowL = mi * 16 + quad * 4 + r;
#pragma unroll
            for (int vni = 0; vni < 4; vni++) {
                const int col = vni * 16 + l16;
                const int g = (col >> 3) ^ (rowL >> 3);
                Ow[rowL * 72 + (col & 7) + (g << 3)] = f2bf(o_[mi][vni][r] * inv);
            }
        }
    }
    LGKM0;   // Ow is wave-private
#pragma unroll
    for (int it = 0; it < 4; it++) {
        const int rowL = it * 8 + (lane >> 3);
        const int c0 = (lane & 7) * 8;
        const int g = (lane & 7) ^ it;            // (c0>>3) ^ (rowL>>3), rowL>>3 == it
        short8 v = *(const short8*)&Ow[rowL * 72 + (g << 3)];
        const int t = q0 + w * 32 + rowL;
        *(short8*)&attb[((size_t)(b * 256 + t)) * 512 + h * 64 + c0] = v;
    }
}

extern "C" void kernel_launch(void* const* d_in, const int* in_sizes, int n_in,
                              void* d_out, int out_size, void* d_ws, size_t ws_size,
                              hipStream_t stream) {
    const float* x    = (const float*)d_in[0];
    const float* cosT = (const float*)d_in[1];
    const float* sinT = (const float*)d_in[2];
    const float* wqkv = (const float*)d_in[3];
    const float* wout = (const float*)d_in[4];
    float* out = (float*)d_out;
    ushort_t* ws = (ushort_t*)d_ws;

    ushort_t* xb    = ws + XB_OFF;
    ushort_t* wqkvb = ws + WQKV_OFF;
    ushort_t* woutb = ws + WOUT_OFF;
    ushort_t* qbp   = ws + QB_OFF;
    ushort_t* kbp   = ws + KB_OFF;
    ushort_t* vbp   = ws + VB_OFF;
    ushort_t* attb  = ws + ATT_OFF;

    convert_k<<<33792, 256, 0, stream>>>(x, wqkv, wout, ws);
    gemm_bt<1><<<6144, 256, 0, stream>>>(xb, wqkvb, nullptr, qbp, kbp, vbp, cosT, sinT);
    attn_k<<<4096, 256, 0, stream>>>(qbp, kbp, vbp, attb);
    gemm_bt<0><<<2048, 256, 0, stream>>>(attb, woutb, out, nullptr, nullptr, nullptr, nullptr, nullptr);
}